// Round 9
// baseline (482.567 us; speedup 1.0000x reference)
//
#include <hip/hip_runtime.h>

#define NN 50000
#define EE 800000

typedef unsigned short u16;
typedef unsigned int u32;
typedef __attribute__((ext_vector_type(8))) short short8;
typedef __attribute__((ext_vector_type(4))) float f32x4;
typedef __attribute__((ext_vector_type(2))) float f32x2;

__device__ __forceinline__ u16 f2bf(float f) {
    union { float f; u32 i; } v; v.f = f;
    u32 x = v.i;
    return (u16)((x + 0x7fffu + ((x >> 16) & 1u)) >> 16);  // RNE (prep only)
}
// pack two f32 -> bf16 pair (round-half-up): 2 add + 1 v_perm
__device__ __forceinline__ u32 pkr(float lo, float hi) {
    union { float f; u32 i; } a, b; a.f = lo; b.f = hi;
    return __builtin_amdgcn_perm(b.i + 0x8000u, a.i + 0x8000u, 0x07060302u);
}
__device__ __forceinline__ float siluf(float x) {
    return x / (1.0f + __expf(-x));
}
__device__ __forceinline__ void atomic_pk_add_bf16(u16* addr, u32 data) {
    asm volatile("global_atomic_pk_add_bf16 %0, %1, off" :: "v"(addr), "v"(data) : "memory");
}

// B layout, column-interleaved tiles: wave=n>>5, parity=n&1, slot=(n>>1)&15
__device__ __forceinline__ int b_idx2(int k, int n) {
    int chunk = ((k >> 5) << 3) + ((n >> 5) << 1) + (n & 1);
    return chunk * 512 + (((k >> 3) & 3) << 7) + (((n >> 1) & 15) << 3) + (k & 7);
}

// ---- h -> bf16 row-major ----
__global__ __launch_bounds__(256) void hconv_kernel(const float* __restrict__ h,
                                                    u16* __restrict__ hbf)
{
    int i = (blockIdx.x * 256 + threadIdx.x) * 8;
    float4 a = *(const float4*)(h + i);
    float4 b = *(const float4*)(h + i + 4);
    uint4 o = make_uint4(pkr(a.x, a.y), pkr(a.z, a.w), pkr(b.x, b.y), pkr(b.z, b.w));
    *(uint4*)(hbf + i) = o;
}

// ---- prep: fp32 weights -> bf16 interleaved fragment layout ----
__global__ __launch_bounds__(256) void prep_kernel(
    const float* __restrict__ We1, const float* __restrict__ We2,
    const float* __restrict__ Wc1, const float* __restrict__ Wn1,
    const float* __restrict__ Wn2, const float* __restrict__ Wv1,
    u16* __restrict__ We1bf, u16* __restrict__ We2bf, u16* __restrict__ Wc1bf,
    u16* __restrict__ Wn1bf, u16* __restrict__ Wn2bf, u16* __restrict__ Wv1bf)
{
    int i = blockIdx.x * 256 + threadIdx.x;     // 0..131071
    if (i < 32768) {
        int k = i >> 7, n = i & 127;
        We1bf[b_idx2(k, n)] = f2bf(We1[k * 128 + n]);   // rows 0..255
    } else if (i < 49152) {
        int t = i - 32768; int k = t >> 7, n = t & 127;
        We2bf[b_idx2(k, n)] = f2bf(We2[k * 128 + n]);
    } else if (i < 65536) {
        int t = i - 49152; int k = t >> 7, n = t & 127;
        Wc1bf[b_idx2(k, n)] = f2bf(Wc1[k * 128 + n]);
    } else if (i < 98304) {
        int t = i - 65536; int k = t >> 7, n = t & 127;
        Wn1bf[b_idx2(k, n)] = f2bf(Wn1[k * 128 + n]);   // rows 0..255
    } else if (i < 114688) {
        int t = i - 98304; int k = t >> 7, n = t & 127;
        Wn2bf[b_idx2(k, n)] = f2bf(Wn2[k * 128 + n]);
    } else {
        int t = i - 114688; int k = t >> 7, n = t & 127;
        Wv1bf[b_idx2(k, n)] = f2bf(Wv1[k * 128 + n]);
    }
}

// ---- edge kernel: 32 edges/block, 4 waves, A-from-global GEMM1, ~19KB LDS ----
__global__ __launch_bounds__(256, 8) void edge_kernel(
    const u16* __restrict__ hbf, const float* __restrict__ cdiff,
    const int* __restrict__ row, const int* __restrict__ col,
    const float* __restrict__ We1, const float* __restrict__ be1,
    const float* __restrict__ be2, const float* __restrict__ bc1,
    const float* __restrict__ Wc2,
    const u16* __restrict__ We1bf, const u16* __restrict__ We2bf,
    const u16* __restrict__ Wc1bf,
    u16* __restrict__ aggbf, float* __restrict__ fsum, float* __restrict__ cnt)
{
    __shared__ u16 sT[4096];       // t1 (A32, K=128, swizzled)
    __shared__ u16 sM[4096];       // m
    __shared__ float sRad[32];
    __shared__ float sW256[128];
    __shared__ float sB1[128], sB2[128], sB3[128];
    __shared__ int sRow[32], sCol[32];
    __shared__ float sCoefP[4][32];

    const int tid = threadIdx.x;
    const int e0 = blockIdx.x * 32;
    const int w = tid >> 6;
    const int lane = tid & 63;
    const int m15 = lane & 15, q = lane >> 4;
    const int n0 = w * 32 + 2 * m15;           // this lane's even col
    const int n1 = n0 + 1;
    const int lsw = (lane ^ q) * 8;            // swizzled fragment read offset (u16)
    const int a_ = m15 >> 2;
    const int sbase = (a_ << 7) + (q << 5) + ((m15 & 3) << 1);
    const int o0 = (0 ^ a_) << 3, o1 = (1 ^ a_) << 3, o2 = (2 ^ a_) << 3, o3 = (3 ^ a_) << 3;

    if (tid < 32) {
        int e = e0 + tid;
        sRow[tid] = row[e]; sCol[tid] = col[e];
        float cx = cdiff[(size_t)e * 3 + 0];
        float cy = cdiff[(size_t)e * 3 + 1];
        float cz = cdiff[(size_t)e * 3 + 2];
        sRad[tid] = cx * cx + cy * cy + cz * cz;
        atomicAdd(&cnt[sRow[tid]], 1.0f);
    }
    if (tid < 128) {
        sW256[tid] = We1[256 * 128 + tid];
        sB1[tid] = be1[tid];
    } else {
        int n = tid - 128;
        sB2[n] = be2[n];
        sB3[n] = bc1[n];
    }
    const float wc2a = Wc2[n0], wc2b = Wc2[n1];
    __syncthreads();

    // per-lane A bases for GEMM1 (direct-from-global fragments)
    const u16* aR0 = hbf + (size_t)sRow[m15] * 128 + q * 8;
    const u16* aC0 = hbf + (size_t)sCol[m15] * 128 + q * 8;
    const u16* aR1 = hbf + (size_t)sRow[16 + m15] * 128 + q * 8;
    const u16* aC1 = hbf + (size_t)sCol[16 + m15] * 128 + q * 8;

    f32x4 acc[2][2];

    // ---- GEMM1: t1 = silu(e_in @ We1 + be1), K=256 + radial rank-1 init ----
    {
        float b0 = sB1[n0], w0 = sW256[n0];
        float b1 = sB1[n1], w1 = sW256[n1];
        #pragma unroll
        for (int mt = 0; mt < 2; ++mt)
            #pragma unroll
            for (int r = 0; r < 4; ++r) {
                float rad = sRad[mt * 16 + q * 4 + r];
                acc[mt][0][r] = fmaf(rad, w0, b0);
                acc[mt][1][r] = fmaf(rad, w1, b1);
            }
    }
    #pragma unroll
    for (int c = 0; c < 8; ++c) {
        short8 bf0 = *(const short8*)(We1bf + (c * 8 + w * 2 + 0) * 512 + lane * 8);
        short8 bf1 = *(const short8*)(We1bf + (c * 8 + w * 2 + 1) * 512 + lane * 8);
        short8 af0 = *(const short8*)((c < 4 ? aR0 : aC0) + (c & 3) * 32);
        short8 af1 = *(const short8*)((c < 4 ? aR1 : aC1) + (c & 3) * 32);
        acc[0][0] = __builtin_amdgcn_mfma_f32_16x16x32_bf16(af0, bf0, acc[0][0], 0, 0, 0);
        acc[0][1] = __builtin_amdgcn_mfma_f32_16x16x32_bf16(af0, bf1, acc[0][1], 0, 0, 0);
        acc[1][0] = __builtin_amdgcn_mfma_f32_16x16x32_bf16(af1, bf0, acc[1][0], 0, 0, 0);
        acc[1][1] = __builtin_amdgcn_mfma_f32_16x16x32_bf16(af1, bf1, acc[1][1], 0, 0, 0);
    }
    u32 d[2][4];
    #pragma unroll
    for (int mt = 0; mt < 2; ++mt)
        #pragma unroll
        for (int r = 0; r < 4; ++r)
            d[mt][r] = pkr(siluf(acc[mt][0][r]), siluf(acc[mt][1][r]));
    #pragma unroll
    for (int mt = 0; mt < 2; ++mt) {
        u16* bp = sT + (w * 2 + mt) * 512 + sbase;
        *(u32*)(bp + o0) = d[mt][0];
        *(u32*)(bp + o1) = d[mt][1];
        *(u32*)(bp + o2) = d[mt][2];
        *(u32*)(bp + o3) = d[mt][3];
    }
    __syncthreads();

    // ---- GEMM2: m = silu(t1 @ We2 + be2), K=128 ----
    {
        float b0 = sB2[n0], b1 = sB2[n1];
        #pragma unroll
        for (int mt = 0; mt < 2; ++mt)
            #pragma unroll
            for (int r = 0; r < 4; ++r) { acc[mt][0][r] = b0; acc[mt][1][r] = b1; }
    }
    #pragma unroll
    for (int c = 0; c < 4; ++c) {
        short8 bf0 = *(const short8*)(We2bf + (c * 8 + w * 2 + 0) * 512 + lane * 8);
        short8 bf1 = *(const short8*)(We2bf + (c * 8 + w * 2 + 1) * 512 + lane * 8);
        #pragma unroll
        for (int mt = 0; mt < 2; ++mt) {
            short8 af = *(const short8*)(sT + (c * 2 + mt) * 512 + lsw);
            acc[mt][0] = __builtin_amdgcn_mfma_f32_16x16x32_bf16(af, bf0, acc[mt][0], 0, 0, 0);
            acc[mt][1] = __builtin_amdgcn_mfma_f32_16x16x32_bf16(af, bf1, acc[mt][1], 0, 0, 0);
        }
    }
    #pragma unroll
    for (int mt = 0; mt < 2; ++mt)
        #pragma unroll
        for (int r = 0; r < 4; ++r)
            d[mt][r] = pkr(siluf(acc[mt][0][r]), siluf(acc[mt][1][r]));
    #pragma unroll
    for (int mt = 0; mt < 2; ++mt) {
        u16* bp = sM + (w * 2 + mt) * 512 + sbase;
        *(u32*)(bp + o0) = d[mt][0];
        *(u32*)(bp + o1) = d[mt][1];
        *(u32*)(bp + o2) = d[mt][2];
        *(u32*)(bp + o3) = d[mt][3];
    }
    #pragma unroll
    for (int mt = 0; mt < 2; ++mt)
        #pragma unroll
        for (int r = 0; r < 4; ++r) {
            int rw = mt * 16 + q * 4 + r;
            atomic_pk_add_bf16(&aggbf[(size_t)sRow[rw] * 128 + n0], d[mt][r]);
        }
    __syncthreads();

    // ---- GEMM3: u = silu(m @ Wc1 + bc1); coef fused via shfl reduce ----
    {
        float b0 = sB3[n0], b1 = sB3[n1];
        #pragma unroll
        for (int mt = 0; mt < 2; ++mt)
            #pragma unroll
            for (int r = 0; r < 4; ++r) { acc[mt][0][r] = b0; acc[mt][1][r] = b1; }
    }
    #pragma unroll
    for (int c = 0; c < 4; ++c) {
        short8 bf0 = *(const short8*)(Wc1bf + (c * 8 + w * 2 + 0) * 512 + lane * 8);
        short8 bf1 = *(const short8*)(Wc1bf + (c * 8 + w * 2 + 1) * 512 + lane * 8);
        #pragma unroll
        for (int mt = 0; mt < 2; ++mt) {
            short8 af = *(const short8*)(sM + (c * 2 + mt) * 512 + lsw);
            acc[mt][0] = __builtin_amdgcn_mfma_f32_16x16x32_bf16(af, bf0, acc[mt][0], 0, 0, 0);
            acc[mt][1] = __builtin_amdgcn_mfma_f32_16x16x32_bf16(af, bf1, acc[mt][1], 0, 0, 0);
        }
    }
    #pragma unroll
    for (int mt = 0; mt < 2; ++mt)
        #pragma unroll
        for (int r = 0; r < 4; ++r) {
            float pv = fmaf(siluf(acc[mt][0][r]), wc2a, siluf(acc[mt][1][r]) * wc2b);
            pv += __shfl_xor(pv, 1);
            pv += __shfl_xor(pv, 2);
            pv += __shfl_xor(pv, 4);
            pv += __shfl_xor(pv, 8);
            if (m15 == 0) sCoefP[w][mt * 16 + q * 4 + r] = pv;
        }
    __syncthreads();

    // force scatter
    if (tid < 96) {
        int e = tid / 3, ax = tid - e * 3;
        float coef = sCoefP[0][e] + sCoefP[1][e] + sCoefP[2][e] + sCoefP[3][e];
        float tr = cdiff[(size_t)(e0 + e) * 3 + ax] * coef;
        tr = fminf(fmaxf(tr, -100.f), 100.f);
        atomicAdd(&fsum[(size_t)sRow[e] * 3 + ax], tr);
    }
}

// ---- node kernel: 64 nodes/block, A-from-global GEMM1/3, ~19KB LDS ----
__global__ __launch_bounds__(256, 6) void node_kernel(
    const u16* __restrict__ hbf,
    const float* __restrict__ bn1, const float* __restrict__ bn2,
    const float* __restrict__ bv1, const float* __restrict__ Wv2,
    const float* __restrict__ bv2,
    const u16* __restrict__ Wn1bf, const u16* __restrict__ Wn2bf,
    const u16* __restrict__ Wv1bf,
    const u16* __restrict__ aggbf, const float* __restrict__ fsum,
    const float* __restrict__ cnt, float* __restrict__ out)
{
    __shared__ u16 sT[8192];       // t (A64 layout, K=128, swizzled) = 16KB
    __shared__ float sBn1[128], sBn2[128], sBv1[128];
    __shared__ float sVelP[4][64];

    const int tid = threadIdx.x;
    const int nblk = blockIdx.x * 64;
    const int w = tid >> 6;
    const int lane = tid & 63;
    const int m15 = lane & 15, q = lane >> 4;
    const int n0 = w * 32 + 2 * m15, n1 = n0 + 1;
    const int lsw = (lane ^ q) * 8;
    const int a_ = m15 >> 2;
    const int sbase = (a_ << 7) + (q << 5) + ((m15 & 3) << 1);
    const int o0 = (0 ^ a_) << 3, o1 = (1 ^ a_) << 3, o2 = (2 ^ a_) << 3, o3 = (3 ^ a_) << 3;

    if (tid < 192) {
        int r = tid / 3, ax = tid - r * 3;
        int n = nblk + r;
        if (n < NN)
            out[NN + (size_t)n * 3 + ax] = fsum[(size_t)n * 3 + ax] / fmaxf(cnt[n], 1.0f);
    }
    if (tid < 128) { sBn1[tid] = bn1[tid]; sBn2[tid] = bn2[tid]; sBv1[tid] = bv1[tid]; }
    const float wv2a = Wv2[n0], wv2b = Wv2[n1];

    // per-lane A bases (rows = nodes, clamped)
    const u16* aH[4];
    const u16* aG[4];
    #pragma unroll
    for (int mt = 0; mt < 4; ++mt) {
        int n = nblk + mt * 16 + m15; if (n > NN - 1) n = NN - 1;
        aH[mt] = hbf + (size_t)n * 128 + q * 8;
        aG[mt] = aggbf + (size_t)n * 128 + q * 8;
    }
    __syncthreads();

    f32x4 acc[4][2];

    // ---- GEMM1: t = silu([h|agg] @ Wn1 + bn1), K=256, A from global ----
    {
        float b0 = sBn1[n0], b1 = sBn1[n1];
        #pragma unroll
        for (int mt = 0; mt < 4; ++mt)
            #pragma unroll
            for (int r = 0; r < 4; ++r) { acc[mt][0][r] = b0; acc[mt][1][r] = b1; }
    }
    #pragma unroll
    for (int c = 0; c < 8; ++c) {
        short8 bf0 = *(const short8*)(Wn1bf + (c * 8 + w * 2 + 0) * 512 + lane * 8);
        short8 bf1 = *(const short8*)(Wn1bf + (c * 8 + w * 2 + 1) * 512 + lane * 8);
        #pragma unroll
        for (int mt = 0; mt < 4; ++mt) {
            short8 af = *(const short8*)((c < 4 ? aH[mt] : aG[mt]) + (c & 3) * 32);
            acc[mt][0] = __builtin_amdgcn_mfma_f32_16x16x32_bf16(af, bf0, acc[mt][0], 0, 0, 0);
            acc[mt][1] = __builtin_amdgcn_mfma_f32_16x16x32_bf16(af, bf1, acc[mt][1], 0, 0, 0);
        }
    }
    u32 dn[4][4];
    #pragma unroll
    for (int mt = 0; mt < 4; ++mt)
        #pragma unroll
        for (int r = 0; r < 4; ++r)
            dn[mt][r] = pkr(siluf(acc[mt][0][r]), siluf(acc[mt][1][r]));
    #pragma unroll
    for (int mt = 0; mt < 4; ++mt) {
        u16* bp = sT + (w * 4 + mt) * 512 + sbase;
        *(u32*)(bp + o0) = dn[mt][0];
        *(u32*)(bp + o1) = dn[mt][1];
        *(u32*)(bp + o2) = dn[mt][2];
        *(u32*)(bp + o3) = dn[mt][3];
    }
    __syncthreads();

    // ---- GEMM2: h_out = t @ Wn2 + bn2, coalesced float2 global stores ----
    {
        float b0 = sBn2[n0], b1 = sBn2[n1];
        #pragma unroll
        for (int mt = 0; mt < 4; ++mt)
            #pragma unroll
            for (int r = 0; r < 4; ++r) { acc[mt][0][r] = b0; acc[mt][1][r] = b1; }
    }
    #pragma unroll
    for (int c = 0; c < 4; ++c) {
        short8 bf0 = *(const short8*)(Wn2bf + (c * 8 + w * 2 + 0) * 512 + lane * 8);
        short8 bf1 = *(const short8*)(Wn2bf + (c * 8 + w * 2 + 1) * 512 + lane * 8);
        #pragma unroll
        for (int mt = 0; mt < 4; ++mt) {
            short8 af = *(const short8*)(sT + (c * 4 + mt) * 512 + lsw);
            acc[mt][0] = __builtin_amdgcn_mfma_f32_16x16x32_bf16(af, bf0, acc[mt][0], 0, 0, 0);
            acc[mt][1] = __builtin_amdgcn_mfma_f32_16x16x32_bf16(af, bf1, acc[mt][1], 0, 0, 0);
        }
    }
    #pragma unroll
    for (int mt = 0; mt < 4; ++mt)
        #pragma unroll
        for (int r = 0; r < 4; ++r) {
            int n = nblk + mt * 16 + q * 4 + r;
            if (n < NN) {
                f32x2 v; v.x = acc[mt][0][r]; v.y = acc[mt][1][r];
                *(f32x2*)(out + (size_t)4 * NN + (size_t)n * 128 + n0) = v;
            }
        }

    // ---- GEMM3: vel head from h (A from global), fused shfl reduce ----
    {
        float b0 = sBv1[n0], b1 = sBv1[n1];
        #pragma unroll
        for (int mt = 0; mt < 4; ++mt)
            #pragma unroll
            for (int r = 0; r < 4; ++r) { acc[mt][0][r] = b0; acc[mt][1][r] = b1; }
    }
    #pragma unroll
    for (int c = 0; c < 4; ++c) {
        short8 bf0 = *(const short8*)(Wv1bf + (c * 8 + w * 2 + 0) * 512 + lane * 8);
        short8 bf1 = *(const short8*)(Wv1bf + (c * 8 + w * 2 + 1) * 512 + lane * 8);
        #pragma unroll
        for (int mt = 0; mt < 4; ++mt) {
            short8 af = *(const short8*)(aH[mt] + (c & 3) * 32);
            acc[mt][0] = __builtin_amdgcn_mfma_f32_16x16x32_bf16(af, bf0, acc[mt][0], 0, 0, 0);
            acc[mt][1] = __builtin_amdgcn_mfma_f32_16x16x32_bf16(af, bf1, acc[mt][1], 0, 0, 0);
        }
    }
    #pragma unroll
    for (int mt = 0; mt < 4; ++mt)
        #pragma unroll
        for (int r = 0; r < 4; ++r) {
            float pv = fmaf(siluf(acc[mt][0][r]), wv2a, siluf(acc[mt][1][r]) * wv2b);
            pv += __shfl_xor(pv, 1);
            pv += __shfl_xor(pv, 2);
            pv += __shfl_xor(pv, 4);
            pv += __shfl_xor(pv, 8);
            if (m15 == 0) sVelP[w][mt * 16 + q * 4 + r] = pv;
        }
    __syncthreads();

    if (tid < 64) {
        int n = nblk + tid;
        if (n < NN)
            out[n] = bv2[0] + sVelP[0][tid] + sVelP[1][tid] + sVelP[2][tid] + sVelP[3][tid];
    }
}

extern "C" void kernel_launch(void* const* d_in, const int* in_sizes, int n_in,
                              void* d_out, int out_size, void* d_ws, size_t ws_size,
                              hipStream_t stream) {
    const float* h     = (const float*)d_in[0];
    const float* cdiff = (const float*)d_in[1];
    const int* row     = (const int*)d_in[2];
    const int* col     = (const int*)d_in[3];
    const float* We1 = (const float*)d_in[4];
    const float* be1 = (const float*)d_in[5];
    const float* We2 = (const float*)d_in[6];
    const float* be2 = (const float*)d_in[7];
    const float* Wn1 = (const float*)d_in[8];
    const float* bn1 = (const float*)d_in[9];
    const float* Wn2 = (const float*)d_in[10];
    const float* bn2 = (const float*)d_in[11];
    const float* Wc1 = (const float*)d_in[12];
    const float* bc1 = (const float*)d_in[13];
    const float* Wc2 = (const float*)d_in[14];
    const float* Wv1 = (const float*)d_in[15];
    const float* bv1 = (const float*)d_in[16];
    const float* Wv2 = (const float*)d_in[17];
    const float* bv2 = (const float*)d_in[18];

    u16* aggbf  = (u16*)d_ws;                           // [NN*128] bf16
    float* fsum = (float*)(aggbf + (size_t)NN * 128);   // [NN*3]
    float* cnt  = fsum + (size_t)NN * 3;                // [NN]
    u16* We1bf = (u16*)(cnt + NN);                      // [32768]
    u16* We2bf = We1bf + 32768;                         // [16384]
    u16* Wc1bf = We2bf + 16384;                         // [16384]
    u16* Wn1bf = Wc1bf + 16384;                         // [32768]
    u16* Wn2bf = Wn1bf + 32768;                         // [16384]
    u16* Wv1bf = Wn2bf + 16384;                         // [16384]
    u16* hbf   = Wv1bf + 16384;                         // [NN*128] bf16
    float* out = (float*)d_out;

    size_t zero_bytes = (size_t)NN * 128 * 2 + (size_t)NN * 3 * 4 + (size_t)NN * 4;
    hipMemsetAsync(d_ws, 0, zero_bytes, stream);

    hconv_kernel<<<3125, 256, 0, stream>>>(h, hbf);
    prep_kernel<<<512, 256, 0, stream>>>(We1, We2, Wc1, Wn1, Wn2, Wv1,
                                         We1bf, We2bf, Wc1bf, Wn1bf, Wn2bf, Wv1bf);
    edge_kernel<<<EE / 32, 256, 0, stream>>>(hbf, cdiff, row, col,
                                             We1, be1, be2, bc1, Wc2,
                                             We1bf, We2bf, Wc1bf,
                                             aggbf, fsum, cnt);
    node_kernel<<<(NN + 63) / 64, 256, 0, stream>>>(hbf, bn1, bn2, bv1, Wv2, bv2,
                                                    Wn1bf, Wn2bf, Wv1bf,
                                                    aggbf, fsum, cnt, out);
}

// Round 10
// 442.635 us; speedup vs baseline: 1.0902x; 1.0902x over previous
//
#include <hip/hip_runtime.h>

#define NN 50000
#define EE 800000

typedef unsigned short u16;
typedef unsigned int u32;
typedef __attribute__((ext_vector_type(8))) short short8;
typedef __attribute__((ext_vector_type(4))) float f32x4;
typedef __attribute__((ext_vector_type(2))) float f32x2;

__device__ __forceinline__ u16 f2bf(float f) {
    union { float f; u32 i; } v; v.f = f;
    u32 x = v.i;
    return (u16)((x + 0x7fffu + ((x >> 16) & 1u)) >> 16);  // RNE (prep only)
}
// pack two f32 -> bf16 pair (round-half-up): 2 add + 1 v_perm
__device__ __forceinline__ u32 pkr(float lo, float hi) {
    union { float f; u32 i; } a, b; a.f = lo; b.f = hi;
    return __builtin_amdgcn_perm(b.i + 0x8000u, a.i + 0x8000u, 0x07060302u);
}
__device__ __forceinline__ float siluf(float x) {
    return x / (1.0f + __expf(-x));
}
__device__ __forceinline__ void atomic_pk_add_bf16(u16* addr, u32 data) {
    asm volatile("global_atomic_pk_add_bf16 %0, %1, off" :: "v"(addr), "v"(data) : "memory");
}

// B layout, column-interleaved tiles: wave=n>>5, parity=n&1, slot=(n>>1)&15
__device__ __forceinline__ int b_idx2(int k, int n) {
    int chunk = ((k >> 5) << 3) + ((n >> 5) << 1) + (n & 1);
    return chunk * 512 + (((k >> 3) & 3) << 7) + (((n >> 1) & 15) << 3) + (k & 7);
}

// ---- h -> bf16 row-major ----
__global__ __launch_bounds__(256) void hconv_kernel(const float* __restrict__ h,
                                                    u16* __restrict__ hbf)
{
    int i = (blockIdx.x * 256 + threadIdx.x) * 8;
    float4 a = *(const float4*)(h + i);
    float4 b = *(const float4*)(h + i + 4);
    uint4 o = make_uint4(pkr(a.x, a.y), pkr(a.z, a.w), pkr(b.x, b.y), pkr(b.z, b.w));
    *(uint4*)(hbf + i) = o;
}

// ---- prep: fp32 weights -> bf16 interleaved fragment layout ----
__global__ __launch_bounds__(256) void prep_kernel(
    const float* __restrict__ We1, const float* __restrict__ We2,
    const float* __restrict__ Wc1, const float* __restrict__ Wn1,
    const float* __restrict__ Wn2, const float* __restrict__ Wv1,
    u16* __restrict__ We1bf, u16* __restrict__ We2bf, u16* __restrict__ Wc1bf,
    u16* __restrict__ Wn1bf, u16* __restrict__ Wn2bf, u16* __restrict__ Wv1bf)
{
    int i = blockIdx.x * 256 + threadIdx.x;     // 0..131071
    if (i < 32768) {
        int k = i >> 7, n = i & 127;
        We1bf[b_idx2(k, n)] = f2bf(We1[k * 128 + n]);   // rows 0..255
    } else if (i < 49152) {
        int t = i - 32768; int k = t >> 7, n = t & 127;
        We2bf[b_idx2(k, n)] = f2bf(We2[k * 128 + n]);
    } else if (i < 65536) {
        int t = i - 49152; int k = t >> 7, n = t & 127;
        Wc1bf[b_idx2(k, n)] = f2bf(Wc1[k * 128 + n]);
    } else if (i < 98304) {
        int t = i - 65536; int k = t >> 7, n = t & 127;
        Wn1bf[b_idx2(k, n)] = f2bf(Wn1[k * 128 + n]);   // rows 0..255
    } else if (i < 114688) {
        int t = i - 98304; int k = t >> 7, n = t & 127;
        Wn2bf[b_idx2(k, n)] = f2bf(Wn2[k * 128 + n]);
    } else {
        int t = i - 114688; int k = t >> 7, n = t & 127;
        Wv1bf[b_idx2(k, n)] = f2bf(Wv1[k * 128 + n]);
    }
}

// ---- edge kernel: 32 edges/block, 4 waves, ~19.5KB LDS, 8 blocks/CU ----
// e_in staging layout: 16B slot(e,kg) = e + 32*kg (kg = k>>3), gather stores
// are wave-contiguous (line-tiled, conflict-free); GEMM1 reads cover full lines.
__global__ __launch_bounds__(256, 8) void edge_kernel(
    const u16* __restrict__ hbf, const float* __restrict__ cdiff,
    const int* __restrict__ row, const int* __restrict__ col,
    const float* __restrict__ We1, const float* __restrict__ be1,
    const float* __restrict__ be2, const float* __restrict__ bc1,
    const float* __restrict__ Wc2,
    const u16* __restrict__ We1bf, const u16* __restrict__ We2bf,
    const u16* __restrict__ Wc1bf,
    u16* __restrict__ aggbf, float* __restrict__ fsum, float* __restrict__ cnt)
{
    __shared__ u16 sA[8192];       // e_in 16KB; lower 8KB->sT, upper->sM after GEMM1
    __shared__ float sRad[32];
    __shared__ float sW256[128];
    __shared__ float sB1[128], sB2[128], sB3[128];
    __shared__ int sRow[32], sCol[32];
    __shared__ float sCoefP[4][32];
    u16* sT = sA;
    u16* sM = sA + 4096;

    const int tid = threadIdx.x;
    const int e0 = blockIdx.x * 32;
    const int w = tid >> 6;
    const int lane = tid & 63;
    const int m15 = lane & 15, q = lane >> 4;
    const int n0 = w * 32 + 2 * m15;           // this lane's even col
    const int n1 = n0 + 1;
    const int lsw = (lane ^ q) * 8;            // swizzled fragment read offset (u16)
    const int a_ = m15 >> 2;
    const int sbase = (a_ << 7) + (q << 5) + ((m15 & 3) << 1);
    const int o0 = (0 ^ a_) << 3, o1 = (1 ^ a_) << 3, o2 = (2 ^ a_) << 3, o3 = (3 ^ a_) << 3;
    const int ard = (m15 + 32 * q) * 8;        // GEMM1 A-read base (u16)

    if (tid < 32) {
        int e = e0 + tid;
        sRow[tid] = row[e]; sCol[tid] = col[e];
        float cx = cdiff[(size_t)e * 3 + 0];
        float cy = cdiff[(size_t)e * 3 + 1];
        float cz = cdiff[(size_t)e * 3 + 2];
        sRad[tid] = cx * cx + cy * cy + cz * cz;
        atomicAdd(&cnt[sRow[tid]], 1.0f);
    }
    if (tid < 128) {
        sW256[tid] = We1[256 * 128 + tid];
        sB1[tid] = be1[tid];
    } else {
        int n = tid - 128;
        sB2[n] = be2[n];
        sB3[n] = bc1[n];
    }
    const float wc2a = Wc2[n0], wc2b = Wc2[n1];
    __syncthreads();

    // gather e_in: thread -> edge tid&31, k-groups kg = 4*(tid>>5)+i
    {
        int e = tid & 31, j = tid >> 5;
        int node = (j < 4) ? sRow[e] : sCol[e];
        const u16* src = hbf + (size_t)node * 128 + (j & 3) * 32;
        #pragma unroll
        for (int i = 0; i < 4; ++i) {
            int slot = e + ((j * 4 + i) << 5);        // e + 32*kg
            *(uint4*)&sA[slot * 8] = *(const uint4*)(src + i * 8);
        }
    }
    __syncthreads();

    f32x4 acc[2][2];

    // ---- GEMM1: t1 = silu(e_in @ We1 + be1), K=256 + radial rank-1 init ----
    {
        float b0 = sB1[n0], w0 = sW256[n0];
        float b1 = sB1[n1], w1 = sW256[n1];
        #pragma unroll
        for (int mt = 0; mt < 2; ++mt)
            #pragma unroll
            for (int r = 0; r < 4; ++r) {
                float rad = sRad[mt * 16 + q * 4 + r];
                acc[mt][0][r] = fmaf(rad, w0, b0);
                acc[mt][1][r] = fmaf(rad, w1, b1);
            }
    }
    #pragma unroll
    for (int c = 0; c < 8; ++c) {
        short8 bf0 = *(const short8*)(We1bf + (c * 8 + w * 2 + 0) * 512 + lane * 8);
        short8 bf1 = *(const short8*)(We1bf + (c * 8 + w * 2 + 1) * 512 + lane * 8);
        #pragma unroll
        for (int mt = 0; mt < 2; ++mt) {
            short8 af = *(const short8*)(sA + ard + c * 1024 + mt * 128);
            acc[mt][0] = __builtin_amdgcn_mfma_f32_16x16x32_bf16(af, bf0, acc[mt][0], 0, 0, 0);
            acc[mt][1] = __builtin_amdgcn_mfma_f32_16x16x32_bf16(af, bf1, acc[mt][1], 0, 0, 0);
        }
    }
    u32 d[2][4];
    #pragma unroll
    for (int mt = 0; mt < 2; ++mt)
        #pragma unroll
        for (int r = 0; r < 4; ++r)
            d[mt][r] = pkr(siluf(acc[mt][0][r]), siluf(acc[mt][1][r]));
    __syncthreads();   // all sA reads done -> aliases writable
    #pragma unroll
    for (int mt = 0; mt < 2; ++mt) {
        u16* bp = sT + (w * 2 + mt) * 512 + sbase;
        *(u32*)(bp + o0) = d[mt][0];
        *(u32*)(bp + o1) = d[mt][1];
        *(u32*)(bp + o2) = d[mt][2];
        *(u32*)(bp + o3) = d[mt][3];
    }
    __syncthreads();

    // ---- GEMM2: m = silu(t1 @ We2 + be2), K=128 ----
    {
        float b0 = sB2[n0], b1 = sB2[n1];
        #pragma unroll
        for (int mt = 0; mt < 2; ++mt)
            #pragma unroll
            for (int r = 0; r < 4; ++r) { acc[mt][0][r] = b0; acc[mt][1][r] = b1; }
    }
    #pragma unroll
    for (int c = 0; c < 4; ++c) {
        short8 bf0 = *(const short8*)(We2bf + (c * 8 + w * 2 + 0) * 512 + lane * 8);
        short8 bf1 = *(const short8*)(We2bf + (c * 8 + w * 2 + 1) * 512 + lane * 8);
        #pragma unroll
        for (int mt = 0; mt < 2; ++mt) {
            short8 af = *(const short8*)(sT + (c * 2 + mt) * 512 + lsw);
            acc[mt][0] = __builtin_amdgcn_mfma_f32_16x16x32_bf16(af, bf0, acc[mt][0], 0, 0, 0);
            acc[mt][1] = __builtin_amdgcn_mfma_f32_16x16x32_bf16(af, bf1, acc[mt][1], 0, 0, 0);
        }
    }
    #pragma unroll
    for (int mt = 0; mt < 2; ++mt)
        #pragma unroll
        for (int r = 0; r < 4; ++r)
            d[mt][r] = pkr(siluf(acc[mt][0][r]), siluf(acc[mt][1][r]));
    // sM region disjoint from sT reads -> no barrier needed before writes
    #pragma unroll
    for (int mt = 0; mt < 2; ++mt) {
        u16* bp = sM + (w * 2 + mt) * 512 + sbase;
        *(u32*)(bp + o0) = d[mt][0];
        *(u32*)(bp + o1) = d[mt][1];
        *(u32*)(bp + o2) = d[mt][2];
        *(u32*)(bp + o3) = d[mt][3];
    }
    #pragma unroll
    for (int mt = 0; mt < 2; ++mt)
        #pragma unroll
        for (int r = 0; r < 4; ++r) {
            int rw = mt * 16 + q * 4 + r;
            atomic_pk_add_bf16(&aggbf[(size_t)sRow[rw] * 128 + n0], d[mt][r]);
        }
    __syncthreads();

    // ---- GEMM3: u = silu(m @ Wc1 + bc1); coef fused via shfl reduce ----
    {
        float b0 = sB3[n0], b1 = sB3[n1];
        #pragma unroll
        for (int mt = 0; mt < 2; ++mt)
            #pragma unroll
            for (int r = 0; r < 4; ++r) { acc[mt][0][r] = b0; acc[mt][1][r] = b1; }
    }
    #pragma unroll
    for (int c = 0; c < 4; ++c) {
        short8 bf0 = *(const short8*)(Wc1bf + (c * 8 + w * 2 + 0) * 512 + lane * 8);
        short8 bf1 = *(const short8*)(Wc1bf + (c * 8 + w * 2 + 1) * 512 + lane * 8);
        #pragma unroll
        for (int mt = 0; mt < 2; ++mt) {
            short8 af = *(const short8*)(sM + (c * 2 + mt) * 512 + lsw);
            acc[mt][0] = __builtin_amdgcn_mfma_f32_16x16x32_bf16(af, bf0, acc[mt][0], 0, 0, 0);
            acc[mt][1] = __builtin_amdgcn_mfma_f32_16x16x32_bf16(af, bf1, acc[mt][1], 0, 0, 0);
        }
    }
    #pragma unroll
    for (int mt = 0; mt < 2; ++mt)
        #pragma unroll
        for (int r = 0; r < 4; ++r) {
            float pv = fmaf(siluf(acc[mt][0][r]), wc2a, siluf(acc[mt][1][r]) * wc2b);
            pv += __shfl_xor(pv, 1);
            pv += __shfl_xor(pv, 2);
            pv += __shfl_xor(pv, 4);
            pv += __shfl_xor(pv, 8);
            if (m15 == 0) sCoefP[w][mt * 16 + q * 4 + r] = pv;
        }
    __syncthreads();

    // force scatter
    if (tid < 96) {
        int e = tid / 3, ax = tid - e * 3;
        float coef = sCoefP[0][e] + sCoefP[1][e] + sCoefP[2][e] + sCoefP[3][e];
        float tr = cdiff[(size_t)(e0 + e) * 3 + ax] * coef;
        tr = fminf(fmaxf(tr, -100.f), 100.f);
        atomicAdd(&fsum[(size_t)sRow[e] * 3 + ax], tr);
    }
}

// ---- node kernel: 64 nodes/block, 4 waves, ~34.5KB LDS, 4 blocks/CU ----
// X staging layout: 16B slot(r,kg) = r + 64*kg; gather stores wave-contiguous.
__global__ __launch_bounds__(256, 4) void node_kernel(
    const u16* __restrict__ hbf,
    const float* __restrict__ bn1, const float* __restrict__ bn2,
    const float* __restrict__ bv1, const float* __restrict__ Wv2,
    const float* __restrict__ bv2,
    const u16* __restrict__ Wn1bf, const u16* __restrict__ Wn2bf,
    const u16* __restrict__ Wv1bf,
    const u16* __restrict__ aggbf, const float* __restrict__ fsum,
    const float* __restrict__ cnt, float* __restrict__ out)
{
    __shared__ u16 sX[16384];      // [h|agg] 32KB; upper 16KB (agg part) -> sT after GEMM1
    __shared__ float sBn1[128], sBn2[128], sBv1[128];
    __shared__ float sVelP[4][64];
    u16* sT = sX + 8192;           // aliases kg>=16 region, dead after GEMM1

    const int tid = threadIdx.x;
    const int nblk = blockIdx.x * 64;
    const int w = tid >> 6;
    const int lane = tid & 63;
    const int m15 = lane & 15, q = lane >> 4;
    const int n0 = w * 32 + 2 * m15, n1 = n0 + 1;
    const int lsw = (lane ^ q) * 8;
    const int a_ = m15 >> 2;
    const int sbase = (a_ << 7) + (q << 5) + ((m15 & 3) << 1);
    const int o0 = (0 ^ a_) << 3, o1 = (1 ^ a_) << 3, o2 = (2 ^ a_) << 3, o3 = (3 ^ a_) << 3;
    const int ard = (m15 + 64 * q) * 8;        // GEMM1/3 A-read base (u16)

    if (tid < 192) {
        int r = tid / 3, ax = tid - r * 3;
        int n = nblk + r;
        if (n < NN)
            out[NN + (size_t)n * 3 + ax] = fsum[(size_t)n * 3 + ax] / fmaxf(cnt[n], 1.0f);
    }
    if (tid < 128) { sBn1[tid] = bn1[tid]; sBn2[tid] = bn2[tid]; sBv1[tid] = bv1[tid]; }
    const float wv2a = Wv2[n0], wv2b = Wv2[n1];

    // gather X = [h | agg]: thread -> row tid&63, kg = 8*(tid>>6)+i
    {
        int r = tid & 63, j = tid >> 6;
        int n = nblk + r; if (n > NN - 1) n = NN - 1;
        const u16* src = ((j < 2) ? hbf : aggbf) + (size_t)n * 128 + (j & 1) * 64;
        #pragma unroll
        for (int i = 0; i < 8; ++i) {
            int slot = r + ((j * 8 + i) << 6);        // r + 64*kg
            *(uint4*)&sX[slot * 8] = *(const uint4*)(src + i * 8);
        }
    }
    __syncthreads();

    f32x4 acc[4][2];

    // ---- GEMM1: t = silu([h|agg] @ Wn1 + bn1), K=256 ----
    {
        float b0 = sBn1[n0], b1 = sBn1[n1];
        #pragma unroll
        for (int mt = 0; mt < 4; ++mt)
            #pragma unroll
            for (int r = 0; r < 4; ++r) { acc[mt][0][r] = b0; acc[mt][1][r] = b1; }
    }
    #pragma unroll
    for (int c = 0; c < 8; ++c) {
        short8 bf0 = *(const short8*)(Wn1bf + (c * 8 + w * 2 + 0) * 512 + lane * 8);
        short8 bf1 = *(const short8*)(Wn1bf + (c * 8 + w * 2 + 1) * 512 + lane * 8);
        #pragma unroll
        for (int mt = 0; mt < 4; ++mt) {
            short8 af = *(const short8*)(sX + ard + c * 2048 + mt * 128);
            acc[mt][0] = __builtin_amdgcn_mfma_f32_16x16x32_bf16(af, bf0, acc[mt][0], 0, 0, 0);
            acc[mt][1] = __builtin_amdgcn_mfma_f32_16x16x32_bf16(af, bf1, acc[mt][1], 0, 0, 0);
        }
    }
    u32 dn[4][4];
    #pragma unroll
    for (int mt = 0; mt < 4; ++mt)
        #pragma unroll
        for (int r = 0; r < 4; ++r)
            dn[mt][r] = pkr(siluf(acc[mt][0][r]), siluf(acc[mt][1][r]));
    __syncthreads();   // sX GEMM1 reads done -> sT alias writable
    #pragma unroll
    for (int mt = 0; mt < 4; ++mt) {
        u16* bp = sT + (w * 4 + mt) * 512 + sbase;
        *(u32*)(bp + o0) = dn[mt][0];
        *(u32*)(bp + o1) = dn[mt][1];
        *(u32*)(bp + o2) = dn[mt][2];
        *(u32*)(bp + o3) = dn[mt][3];
    }
    __syncthreads();

    // ---- GEMM2: h_out = t @ Wn2 + bn2, coalesced float2 global stores ----
    {
        float b0 = sBn2[n0], b1 = sBn2[n1];
        #pragma unroll
        for (int mt = 0; mt < 4; ++mt)
            #pragma unroll
            for (int r = 0; r < 4; ++r) { acc[mt][0][r] = b0; acc[mt][1][r] = b1; }
    }
    #pragma unroll
    for (int c = 0; c < 4; ++c) {
        short8 bf0 = *(const short8*)(Wn2bf + (c * 8 + w * 2 + 0) * 512 + lane * 8);
        short8 bf1 = *(const short8*)(Wn2bf + (c * 8 + w * 2 + 1) * 512 + lane * 8);
        #pragma unroll
        for (int mt = 0; mt < 4; ++mt) {
            short8 af = *(const short8*)(sT + (c * 4 + mt) * 512 + lsw);
            acc[mt][0] = __builtin_amdgcn_mfma_f32_16x16x32_bf16(af, bf0, acc[mt][0], 0, 0, 0);
            acc[mt][1] = __builtin_amdgcn_mfma_f32_16x16x32_bf16(af, bf1, acc[mt][1], 0, 0, 0);
        }
    }
    #pragma unroll
    for (int mt = 0; mt < 4; ++mt)
        #pragma unroll
        for (int r = 0; r < 4; ++r) {
            int n = nblk + mt * 16 + q * 4 + r;
            if (n < NN) {
                f32x2 v; v.x = acc[mt][0][r]; v.y = acc[mt][1][r];
                *(f32x2*)(out + (size_t)4 * NN + (size_t)n * 128 + n0) = v;
            }
        }

    // ---- GEMM3: vel head from h (sX kg<16), fused shfl reduce ----
    {
        float b0 = sBv1[n0], b1 = sBv1[n1];
        #pragma unroll
        for (int mt = 0; mt < 4; ++mt)
            #pragma unroll
            for (int r = 0; r < 4; ++r) { acc[mt][0][r] = b0; acc[mt][1][r] = b1; }
    }
    #pragma unroll
    for (int c = 0; c < 4; ++c) {
        short8 bf0 = *(const short8*)(Wv1bf + (c * 8 + w * 2 + 0) * 512 + lane * 8);
        short8 bf1 = *(const short8*)(Wv1bf + (c * 8 + w * 2 + 1) * 512 + lane * 8);
        #pragma unroll
        for (int mt = 0; mt < 4; ++mt) {
            short8 af = *(const short8*)(sX + ard + c * 2048 + mt * 128);
            acc[mt][0] = __builtin_amdgcn_mfma_f32_16x16x32_bf16(af, bf0, acc[mt][0], 0, 0, 0);
            acc[mt][1] = __builtin_amdgcn_mfma_f32_16x16x32_bf16(af, bf1, acc[mt][1], 0, 0, 0);
        }
    }
    #pragma unroll
    for (int mt = 0; mt < 4; ++mt)
        #pragma unroll
        for (int r = 0; r < 4; ++r) {
            float pv = fmaf(siluf(acc[mt][0][r]), wv2a, siluf(acc[mt][1][r]) * wv2b);
            pv += __shfl_xor(pv, 1);
            pv += __shfl_xor(pv, 2);
            pv += __shfl_xor(pv, 4);
            pv += __shfl_xor(pv, 8);
            if (m15 == 0) sVelP[w][mt * 16 + q * 4 + r] = pv;
        }
    __syncthreads();

    if (tid < 64) {
        int n = nblk + tid;
        if (n < NN)
            out[n] = bv2[0] + sVelP[0][tid] + sVelP[1][tid] + sVelP[2][tid] + sVelP[3][tid];
    }
}

extern "C" void kernel_launch(void* const* d_in, const int* in_sizes, int n_in,
                              void* d_out, int out_size, void* d_ws, size_t ws_size,
                              hipStream_t stream) {
    const float* h     = (const float*)d_in[0];
    const float* cdiff = (const float*)d_in[1];
    const int* row     = (const int*)d_in[2];
    const int* col     = (const int*)d_in[3];
    const float* We1 = (const float*)d_in[4];
    const float* be1 = (const float*)d_in[5];
    const float* We2 = (const float*)d_in[6];
    const float* be2 = (const float*)d_in[7];
    const float* Wn1 = (const float*)d_in[8];
    const float* bn1 = (const float*)d_in[9];
    const float* Wn2 = (const float*)d_in[10];
    const float* bn2 = (const float*)d_in[11];
    const float* Wc1 = (const float*)d_in[12];
    const float* bc1 = (const float*)d_in[13];
    const float* Wc2 = (const float*)d_in[14];
    const float* Wv1 = (const float*)d_in[15];
    const float* bv1 = (const float*)d_in[16];
    const float* Wv2 = (const float*)d_in[17];
    const float* bv2 = (const float*)d_in[18];

    u16* aggbf  = (u16*)d_ws;                           // [NN*128] bf16
    float* fsum = (float*)(aggbf + (size_t)NN * 128);   // [NN*3]
    float* cnt  = fsum + (size_t)NN * 3;                // [NN]
    u16* We1bf = (u16*)(cnt + NN);                      // [32768]
    u16* We2bf = We1bf + 32768;                         // [16384]
    u16* Wc1bf = We2bf + 16384;                         // [16384]
    u16* Wn1bf = Wc1bf + 16384;                         // [32768]
    u16* Wn2bf = Wn1bf + 32768;                         // [16384]
    u16* Wv1bf = Wn2bf + 16384;                         // [16384]
    u16* hbf   = Wv1bf + 16384;                         // [NN*128] bf16
    float* out = (float*)d_out;

    size_t zero_bytes = (size_t)NN * 128 * 2 + (size_t)NN * 3 * 4 + (size_t)NN * 4;
    hipMemsetAsync(d_ws, 0, zero_bytes, stream);

    hconv_kernel<<<3125, 256, 0, stream>>>(h, hbf);
    prep_kernel<<<512, 256, 0, stream>>>(We1, We2, Wc1, Wn1, Wn2, Wv1,
                                         We1bf, We2bf, Wc1bf, Wn1bf, Wn2bf, Wv1bf);
    edge_kernel<<<EE / 32, 256, 0, stream>>>(hbf, cdiff, row, col,
                                             We1, be1, be2, bc1, Wc2,
                                             We1bf, We2bf, Wc1bf,
                                             aggbf, fsum, cnt);
    node_kernel<<<(NN + 63) / 64, 256, 0, stream>>>(hbf, bn1, bn2, bv1, Wv2, bv2,
                                                    Wn1bf, Wn2bf, Wv1bf,
                                                    aggbf, fsum, cnt, out);
}

// Round 11
// 417.663 us; speedup vs baseline: 1.1554x; 1.0598x over previous
//
#include <hip/hip_runtime.h>

#define NN 50000
#define EE 800000

typedef unsigned short u16;
typedef unsigned int u32;
typedef __attribute__((ext_vector_type(8))) short short8;
typedef __attribute__((ext_vector_type(4))) float f32x4;
typedef __attribute__((ext_vector_type(2))) float f32x2;

__device__ __forceinline__ u16 f2bf(float f) {
    union { float f; u32 i; } v; v.f = f;
    u32 x = v.i;
    return (u16)((x + 0x7fffu + ((x >> 16) & 1u)) >> 16);  // RNE (prep only)
}
// pack two f32 -> bf16 pair (round-half-up): 2 add + 1 v_perm
__device__ __forceinline__ u32 pkr(float lo, float hi) {
    union { float f; u32 i; } a, b; a.f = lo; b.f = hi;
    return __builtin_amdgcn_perm(b.i + 0x8000u, a.i + 0x8000u, 0x07060302u);
}
// silu via hw rcp: avoids IEEE div sequence (v_div_scale/fmas/fixup ~12 inst)
__device__ __forceinline__ float siluf(float x) {
    return x * __builtin_amdgcn_rcpf(1.0f + __expf(-x));
}
__device__ __forceinline__ void atomic_pk_add_bf16(u16* addr, u32 data) {
    asm volatile("global_atomic_pk_add_bf16 %0, %1, off" :: "v"(addr), "v"(data) : "memory");
}

// B layout, column-interleaved tiles: wave=n>>5, parity=n&1, slot=(n>>1)&15
__device__ __forceinline__ int b_idx2(int k, int n) {
    int chunk = ((k >> 5) << 3) + ((n >> 5) << 1) + (n & 1);
    return chunk * 512 + (((k >> 3) & 3) << 7) + (((n >> 1) & 15) << 3) + (k & 7);
}

// ---- h -> bf16 row-major ----
__global__ __launch_bounds__(256) void hconv_kernel(const float* __restrict__ h,
                                                    u16* __restrict__ hbf)
{
    int i = (blockIdx.x * 256 + threadIdx.x) * 8;
    float4 a = *(const float4*)(h + i);
    float4 b = *(const float4*)(h + i + 4);
    uint4 o = make_uint4(pkr(a.x, a.y), pkr(a.z, a.w), pkr(b.x, b.y), pkr(b.z, b.w));
    *(uint4*)(hbf + i) = o;
}

// ---- prep: fp32 weights -> bf16 interleaved fragment layout ----
__global__ __launch_bounds__(256) void prep_kernel(
    const float* __restrict__ We1, const float* __restrict__ We2,
    const float* __restrict__ Wc1, const float* __restrict__ Wn1,
    const float* __restrict__ Wn2, const float* __restrict__ Wv1,
    u16* __restrict__ We1bf, u16* __restrict__ We2bf, u16* __restrict__ Wc1bf,
    u16* __restrict__ Wn1bf, u16* __restrict__ Wn2bf, u16* __restrict__ Wv1bf)
{
    int i = blockIdx.x * 256 + threadIdx.x;     // 0..131071
    if (i < 32768) {
        int k = i >> 7, n = i & 127;
        We1bf[b_idx2(k, n)] = f2bf(We1[k * 128 + n]);   // rows 0..255
    } else if (i < 49152) {
        int t = i - 32768; int k = t >> 7, n = t & 127;
        We2bf[b_idx2(k, n)] = f2bf(We2[k * 128 + n]);
    } else if (i < 65536) {
        int t = i - 49152; int k = t >> 7, n = t & 127;
        Wc1bf[b_idx2(k, n)] = f2bf(Wc1[k * 128 + n]);
    } else if (i < 98304) {
        int t = i - 65536; int k = t >> 7, n = t & 127;
        Wn1bf[b_idx2(k, n)] = f2bf(Wn1[k * 128 + n]);   // rows 0..255
    } else if (i < 114688) {
        int t = i - 98304; int k = t >> 7, n = t & 127;
        Wn2bf[b_idx2(k, n)] = f2bf(Wn2[k * 128 + n]);
    } else {
        int t = i - 114688; int k = t >> 7, n = t & 127;
        Wv1bf[b_idx2(k, n)] = f2bf(Wv1[k * 128 + n]);
    }
}

// ---- edge kernel: 32 edges/block, 4 waves, ~19.5KB LDS, 8 blocks/CU ----
// e_in staging layout: 16B slot(e,kg) = e + 32*kg (kg = k>>3), gather stores
// are wave-contiguous (line-tiled, conflict-free); GEMM1 reads cover full lines.
__global__ __launch_bounds__(256, 8) void edge_kernel(
    const u16* __restrict__ hbf, const float* __restrict__ cdiff,
    const int* __restrict__ row, const int* __restrict__ col,
    const float* __restrict__ We1, const float* __restrict__ be1,
    const float* __restrict__ be2, const float* __restrict__ bc1,
    const float* __restrict__ Wc2,
    const u16* __restrict__ We1bf, const u16* __restrict__ We2bf,
    const u16* __restrict__ Wc1bf,
    u16* __restrict__ aggbf, float* __restrict__ fsum, float* __restrict__ cnt)
{
    __shared__ u16 sA[8192];       // e_in 16KB; lower 8KB->sT, upper->sM after GEMM1
    __shared__ float sRad[32];
    __shared__ float sW256[128];
    __shared__ float sB1[128], sB2[128], sB3[128];
    __shared__ int sRow[32], sCol[32];
    __shared__ float sCoefP[4][32];
    u16* sT = sA;
    u16* sM = sA + 4096;

    const int tid = threadIdx.x;
    const int e0 = blockIdx.x * 32;
    const int w = tid >> 6;
    const int lane = tid & 63;
    const int m15 = lane & 15, q = lane >> 4;
    const int n0 = w * 32 + 2 * m15;           // this lane's even col
    const int n1 = n0 + 1;
    const int lsw = (lane ^ q) * 8;            // swizzled fragment read offset (u16)
    const int a_ = m15 >> 2;
    const int sbase = (a_ << 7) + (q << 5) + ((m15 & 3) << 1);
    const int o0 = (0 ^ a_) << 3, o1 = (1 ^ a_) << 3, o2 = (2 ^ a_) << 3, o3 = (3 ^ a_) << 3;
    const int ard = (m15 + 32 * q) * 8;        // GEMM1 A-read base (u16)

    if (tid < 32) {
        int e = e0 + tid;
        sRow[tid] = row[e]; sCol[tid] = col[e];
        float cx = cdiff[(size_t)e * 3 + 0];
        float cy = cdiff[(size_t)e * 3 + 1];
        float cz = cdiff[(size_t)e * 3 + 2];
        sRad[tid] = cx * cx + cy * cy + cz * cz;
        atomicAdd(&cnt[sRow[tid]], 1.0f);
    }
    if (tid < 128) {
        sW256[tid] = We1[256 * 128 + tid];
        sB1[tid] = be1[tid];
    } else {
        int n = tid - 128;
        sB2[n] = be2[n];
        sB3[n] = bc1[n];
    }
    const float wc2a = Wc2[n0], wc2b = Wc2[n1];
    __syncthreads();

    // gather e_in: thread -> edge tid&31, k-groups kg = 4*(tid>>5)+i
    {
        int e = tid & 31, j = tid >> 5;
        int node = (j < 4) ? sRow[e] : sCol[e];
        const u16* src = hbf + (size_t)node * 128 + (j & 3) * 32;
        #pragma unroll
        for (int i = 0; i < 4; ++i) {
            int slot = e + ((j * 4 + i) << 5);        // e + 32*kg
            *(uint4*)&sA[slot * 8] = *(const uint4*)(src + i * 8);
        }
    }
    __syncthreads();

    f32x4 acc[2][2];

    // ---- GEMM1: t1 = silu(e_in @ We1 + be1), K=256 + radial rank-1 init ----
    {
        float b0 = sB1[n0], w0 = sW256[n0];
        float b1 = sB1[n1], w1 = sW256[n1];
        #pragma unroll
        for (int mt = 0; mt < 2; ++mt)
            #pragma unroll
            for (int r = 0; r < 4; ++r) {
                float rad = sRad[mt * 16 + q * 4 + r];
                acc[mt][0][r] = fmaf(rad, w0, b0);
                acc[mt][1][r] = fmaf(rad, w1, b1);
            }
    }
    #pragma unroll
    for (int c = 0; c < 8; ++c) {
        short8 bf0 = *(const short8*)(We1bf + (c * 8 + w * 2 + 0) * 512 + lane * 8);
        short8 bf1 = *(const short8*)(We1bf + (c * 8 + w * 2 + 1) * 512 + lane * 8);
        #pragma unroll
        for (int mt = 0; mt < 2; ++mt) {
            short8 af = *(const short8*)(sA + ard + c * 1024 + mt * 128);
            acc[mt][0] = __builtin_amdgcn_mfma_f32_16x16x32_bf16(af, bf0, acc[mt][0], 0, 0, 0);
            acc[mt][1] = __builtin_amdgcn_mfma_f32_16x16x32_bf16(af, bf1, acc[mt][1], 0, 0, 0);
        }
    }
    u32 d[2][4];
    #pragma unroll
    for (int mt = 0; mt < 2; ++mt)
        #pragma unroll
        for (int r = 0; r < 4; ++r)
            d[mt][r] = pkr(siluf(acc[mt][0][r]), siluf(acc[mt][1][r]));
    __syncthreads();   // all sA reads done -> aliases writable
    #pragma unroll
    for (int mt = 0; mt < 2; ++mt) {
        u16* bp = sT + (w * 2 + mt) * 512 + sbase;
        *(u32*)(bp + o0) = d[mt][0];
        *(u32*)(bp + o1) = d[mt][1];
        *(u32*)(bp + o2) = d[mt][2];
        *(u32*)(bp + o3) = d[mt][3];
    }
    __syncthreads();

    // ---- GEMM2: m = silu(t1 @ We2 + be2), K=128 ----
    {
        float b0 = sB2[n0], b1 = sB2[n1];
        #pragma unroll
        for (int mt = 0; mt < 2; ++mt)
            #pragma unroll
            for (int r = 0; r < 4; ++r) { acc[mt][0][r] = b0; acc[mt][1][r] = b1; }
    }
    #pragma unroll
    for (int c = 0; c < 4; ++c) {
        short8 bf0 = *(const short8*)(We2bf + (c * 8 + w * 2 + 0) * 512 + lane * 8);
        short8 bf1 = *(const short8*)(We2bf + (c * 8 + w * 2 + 1) * 512 + lane * 8);
        #pragma unroll
        for (int mt = 0; mt < 2; ++mt) {
            short8 af = *(const short8*)(sT + (c * 2 + mt) * 512 + lsw);
            acc[mt][0] = __builtin_amdgcn_mfma_f32_16x16x32_bf16(af, bf0, acc[mt][0], 0, 0, 0);
            acc[mt][1] = __builtin_amdgcn_mfma_f32_16x16x32_bf16(af, bf1, acc[mt][1], 0, 0, 0);
        }
    }
    #pragma unroll
    for (int mt = 0; mt < 2; ++mt)
        #pragma unroll
        for (int r = 0; r < 4; ++r)
            d[mt][r] = pkr(siluf(acc[mt][0][r]), siluf(acc[mt][1][r]));
    // sM region disjoint from sT reads -> no barrier needed before writes
    #pragma unroll
    for (int mt = 0; mt < 2; ++mt) {
        u16* bp = sM + (w * 2 + mt) * 512 + sbase;
        *(u32*)(bp + o0) = d[mt][0];
        *(u32*)(bp + o1) = d[mt][1];
        *(u32*)(bp + o2) = d[mt][2];
        *(u32*)(bp + o3) = d[mt][3];
    }
    #pragma unroll
    for (int mt = 0; mt < 2; ++mt)
        #pragma unroll
        for (int r = 0; r < 4; ++r) {
            int rw = mt * 16 + q * 4 + r;
            atomic_pk_add_bf16(&aggbf[(size_t)sRow[rw] * 128 + n0], d[mt][r]);
        }
    __syncthreads();

    // ---- GEMM3: u = silu(m @ Wc1 + bc1); coef fused via shfl reduce ----
    {
        float b0 = sB3[n0], b1 = sB3[n1];
        #pragma unroll
        for (int mt = 0; mt < 2; ++mt)
            #pragma unroll
            for (int r = 0; r < 4; ++r) { acc[mt][0][r] = b0; acc[mt][1][r] = b1; }
    }
    #pragma unroll
    for (int c = 0; c < 4; ++c) {
        short8 bf0 = *(const short8*)(Wc1bf + (c * 8 + w * 2 + 0) * 512 + lane * 8);
        short8 bf1 = *(const short8*)(Wc1bf + (c * 8 + w * 2 + 1) * 512 + lane * 8);
        #pragma unroll
        for (int mt = 0; mt < 2; ++mt) {
            short8 af = *(const short8*)(sM + (c * 2 + mt) * 512 + lsw);
            acc[mt][0] = __builtin_amdgcn_mfma_f32_16x16x32_bf16(af, bf0, acc[mt][0], 0, 0, 0);
            acc[mt][1] = __builtin_amdgcn_mfma_f32_16x16x32_bf16(af, bf1, acc[mt][1], 0, 0, 0);
        }
    }
    #pragma unroll
    for (int mt = 0; mt < 2; ++mt)
        #pragma unroll
        for (int r = 0; r < 4; ++r) {
            float pv = fmaf(siluf(acc[mt][0][r]), wc2a, siluf(acc[mt][1][r]) * wc2b);
            pv += __shfl_xor(pv, 1);
            pv += __shfl_xor(pv, 2);
            pv += __shfl_xor(pv, 4);
            pv += __shfl_xor(pv, 8);
            if (m15 == 0) sCoefP[w][mt * 16 + q * 4 + r] = pv;
        }
    __syncthreads();

    // force scatter
    if (tid < 96) {
        int e = tid / 3, ax = tid - e * 3;
        float coef = sCoefP[0][e] + sCoefP[1][e] + sCoefP[2][e] + sCoefP[3][e];
        float tr = cdiff[(size_t)(e0 + e) * 3 + ax] * coef;
        tr = fminf(fmaxf(tr, -100.f), 100.f);
        atomicAdd(&fsum[(size_t)sRow[e] * 3 + ax], tr);
    }
}

// ---- node kernel: 64 nodes/block, 4 waves, ~34.5KB LDS, 4 blocks/CU ----
// X staging layout: 16B slot(r,kg) = r + 64*kg; gather stores wave-contiguous.
__global__ __launch_bounds__(256, 4) void node_kernel(
    const u16* __restrict__ hbf,
    const float* __restrict__ bn1, const float* __restrict__ bn2,
    const float* __restrict__ bv1, const float* __restrict__ Wv2,
    const float* __restrict__ bv2,
    const u16* __restrict__ Wn1bf, const u16* __restrict__ Wn2bf,
    const u16* __restrict__ Wv1bf,
    const u16* __restrict__ aggbf, const float* __restrict__ fsum,
    const float* __restrict__ cnt, float* __restrict__ out)
{
    __shared__ u16 sX[16384];      // [h|agg] 32KB; upper 16KB (agg part) -> sT after GEMM1
    __shared__ float sBn1[128], sBn2[128], sBv1[128];
    __shared__ float sVelP[4][64];
    u16* sT = sX + 8192;           // aliases kg>=16 region, dead after GEMM1

    const int tid = threadIdx.x;
    const int nblk = blockIdx.x * 64;
    const int w = tid >> 6;
    const int lane = tid & 63;
    const int m15 = lane & 15, q = lane >> 4;
    const int n0 = w * 32 + 2 * m15, n1 = n0 + 1;
    const int lsw = (lane ^ q) * 8;
    const int a_ = m15 >> 2;
    const int sbase = (a_ << 7) + (q << 5) + ((m15 & 3) << 1);
    const int o0 = (0 ^ a_) << 3, o1 = (1 ^ a_) << 3, o2 = (2 ^ a_) << 3, o3 = (3 ^ a_) << 3;
    const int ard = (m15 + 64 * q) * 8;        // GEMM1/3 A-read base (u16)

    if (tid < 192) {
        int r = tid / 3, ax = tid - r * 3;
        int n = nblk + r;
        if (n < NN)
            out[NN + (size_t)n * 3 + ax] = fsum[(size_t)n * 3 + ax] * __builtin_amdgcn_rcpf(fmaxf(cnt[n], 1.0f));
    }
    if (tid < 128) { sBn1[tid] = bn1[tid]; sBn2[tid] = bn2[tid]; sBv1[tid] = bv1[tid]; }
    const float wv2a = Wv2[n0], wv2b = Wv2[n1];

    // gather X = [h | agg]: thread -> row tid&63, kg = 8*(tid>>6)+i
    {
        int r = tid & 63, j = tid >> 6;
        int n = nblk + r; if (n > NN - 1) n = NN - 1;
        const u16* src = ((j < 2) ? hbf : aggbf) + (size_t)n * 128 + (j & 1) * 64;
        #pragma unroll
        for (int i = 0; i < 8; ++i) {
            int slot = r + ((j * 8 + i) << 6);        // r + 64*kg
            *(uint4*)&sX[slot * 8] = *(const uint4*)(src + i * 8);
        }
    }
    __syncthreads();

    f32x4 acc[4][2];

    // ---- GEMM1: t = silu([h|agg] @ Wn1 + bn1), K=256 ----
    {
        float b0 = sBn1[n0], b1 = sBn1[n1];
        #pragma unroll
        for (int mt = 0; mt < 4; ++mt)
            #pragma unroll
            for (int r = 0; r < 4; ++r) { acc[mt][0][r] = b0; acc[mt][1][r] = b1; }
    }
    #pragma unroll
    for (int c = 0; c < 8; ++c) {
        short8 bf0 = *(const short8*)(Wn1bf + (c * 8 + w * 2 + 0) * 512 + lane * 8);
        short8 bf1 = *(const short8*)(Wn1bf + (c * 8 + w * 2 + 1) * 512 + lane * 8);
        #pragma unroll
        for (int mt = 0; mt < 4; ++mt) {
            short8 af = *(const short8*)(sX + ard + c * 2048 + mt * 128);
            acc[mt][0] = __builtin_amdgcn_mfma_f32_16x16x32_bf16(af, bf0, acc[mt][0], 0, 0, 0);
            acc[mt][1] = __builtin_amdgcn_mfma_f32_16x16x32_bf16(af, bf1, acc[mt][1], 0, 0, 0);
        }
    }
    u32 dn[4][4];
    #pragma unroll
    for (int mt = 0; mt < 4; ++mt)
        #pragma unroll
        for (int r = 0; r < 4; ++r)
            dn[mt][r] = pkr(siluf(acc[mt][0][r]), siluf(acc[mt][1][r]));
    __syncthreads();   // sX GEMM1 reads done -> sT alias writable
    #pragma unroll
    for (int mt = 0; mt < 4; ++mt) {
        u16* bp = sT + (w * 4 + mt) * 512 + sbase;
        *(u32*)(bp + o0) = dn[mt][0];
        *(u32*)(bp + o1) = dn[mt][1];
        *(u32*)(bp + o2) = dn[mt][2];
        *(u32*)(bp + o3) = dn[mt][3];
    }
    __syncthreads();

    // ---- GEMM2: h_out = t @ Wn2 + bn2, coalesced float2 global stores ----
    {
        float b0 = sBn2[n0], b1 = sBn2[n1];
        #pragma unroll
        for (int mt = 0; mt < 4; ++mt)
            #pragma unroll
            for (int r = 0; r < 4; ++r) { acc[mt][0][r] = b0; acc[mt][1][r] = b1; }
    }
    #pragma unroll
    for (int c = 0; c < 4; ++c) {
        short8 bf0 = *(const short8*)(Wn2bf + (c * 8 + w * 2 + 0) * 512 + lane * 8);
        short8 bf1 = *(const short8*)(Wn2bf + (c * 8 + w * 2 + 1) * 512 + lane * 8);
        #pragma unroll
        for (int mt = 0; mt < 4; ++mt) {
            short8 af = *(const short8*)(sT + (c * 4 + mt) * 512 + lsw);
            acc[mt][0] = __builtin_amdgcn_mfma_f32_16x16x32_bf16(af, bf0, acc[mt][0], 0, 0, 0);
            acc[mt][1] = __builtin_amdgcn_mfma_f32_16x16x32_bf16(af, bf1, acc[mt][1], 0, 0, 0);
        }
    }
    #pragma unroll
    for (int mt = 0; mt < 4; ++mt)
        #pragma unroll
        for (int r = 0; r < 4; ++r) {
            int n = nblk + mt * 16 + q * 4 + r;
            if (n < NN) {
                f32x2 v; v.x = acc[mt][0][r]; v.y = acc[mt][1][r];
                *(f32x2*)(out + (size_t)4 * NN + (size_t)n * 128 + n0) = v;
            }
        }

    // ---- GEMM3: vel head from h (sX kg<16), fused shfl reduce ----
    {
        float b0 = sBv1[n0], b1 = sBv1[n1];
        #pragma unroll
        for (int mt = 0; mt < 4; ++mt)
            #pragma unroll
            for (int r = 0; r < 4; ++r) { acc[mt][0][r] = b0; acc[mt][1][r] = b1; }
    }
    #pragma unroll
    for (int c = 0; c < 4; ++c) {
        short8 bf0 = *(const short8*)(Wv1bf + (c * 8 + w * 2 + 0) * 512 + lane * 8);
        short8 bf1 = *(const short8*)(Wv1bf + (c * 8 + w * 2 + 1) * 512 + lane * 8);
        #pragma unroll
        for (int mt = 0; mt < 4; ++mt) {
            short8 af = *(const short8*)(sX + ard + c * 2048 + mt * 128);
            acc[mt][0] = __builtin_amdgcn_mfma_f32_16x16x32_bf16(af, bf0, acc[mt][0], 0, 0, 0);
            acc[mt][1] = __builtin_amdgcn_mfma_f32_16x16x32_bf16(af, bf1, acc[mt][1], 0, 0, 0);
        }
    }
    #pragma unroll
    for (int mt = 0; mt < 4; ++mt)
        #pragma unroll
        for (int r = 0; r < 4; ++r) {
            float pv = fmaf(siluf(acc[mt][0][r]), wv2a, siluf(acc[mt][1][r]) * wv2b);
            pv += __shfl_xor(pv, 1);
            pv += __shfl_xor(pv, 2);
            pv += __shfl_xor(pv, 4);
            pv += __shfl_xor(pv, 8);
            if (m15 == 0) sVelP[w][mt * 16 + q * 4 + r] = pv;
        }
    __syncthreads();

    if (tid < 64) {
        int n = nblk + tid;
        if (n < NN)
            out[n] = bv2[0] + sVelP[0][tid] + sVelP[1][tid] + sVelP[2][tid] + sVelP[3][tid];
    }
}

extern "C" void kernel_launch(void* const* d_in, const int* in_sizes, int n_in,
                              void* d_out, int out_size, void* d_ws, size_t ws_size,
                              hipStream_t stream) {
    const float* h     = (const float*)d_in[0];
    const float* cdiff = (const float*)d_in[1];
    const int* row     = (const int*)d_in[2];
    const int* col     = (const int*)d_in[3];
    const float* We1 = (const float*)d_in[4];
    const float* be1 = (const float*)d_in[5];
    const float* We2 = (const float*)d_in[6];
    const float* be2 = (const float*)d_in[7];
    const float* Wn1 = (const float*)d_in[8];
    const float* bn1 = (const float*)d_in[9];
    const float* Wn2 = (const float*)d_in[10];
    const float* bn2 = (const float*)d_in[11];
    const float* Wc1 = (const float*)d_in[12];
    const float* bc1 = (const float*)d_in[13];
    const float* Wc2 = (const float*)d_in[14];
    const float* Wv1 = (const float*)d_in[15];
    const float* bv1 = (const float*)d_in[16];
    const float* Wv2 = (const float*)d_in[17];
    const float* bv2 = (const float*)d_in[18];

    u16* aggbf  = (u16*)d_ws;                           // [NN*128] bf16
    float* fsum = (float*)(aggbf + (size_t)NN * 128);   // [NN*3]
    float* cnt  = fsum + (size_t)NN * 3;                // [NN]
    u16* We1bf = (u16*)(cnt + NN);                      // [32768]
    u16* We2bf = We1bf + 32768;                         // [16384]
    u16* Wc1bf = We2bf + 16384;                         // [16384]
    u16* Wn1bf = Wc1bf + 16384;                         // [32768]
    u16* Wn2bf = Wn1bf + 32768;                         // [16384]
    u16* Wv1bf = Wn2bf + 16384;                         // [16384]
    u16* hbf   = Wv1bf + 16384;                         // [NN*128] bf16
    float* out = (float*)d_out;

    size_t zero_bytes = (size_t)NN * 128 * 2 + (size_t)NN * 3 * 4 + (size_t)NN * 4;
    hipMemsetAsync(d_ws, 0, zero_bytes, stream);

    hconv_kernel<<<3125, 256, 0, stream>>>(h, hbf);
    prep_kernel<<<512, 256, 0, stream>>>(We1, We2, Wc1, Wn1, Wn2, Wv1,
                                         We1bf, We2bf, Wc1bf, Wn1bf, Wn2bf, Wv1bf);
    edge_kernel<<<EE / 32, 256, 0, stream>>>(hbf, cdiff, row, col,
                                             We1, be1, be2, bc1, Wc2,
                                             We1bf, We2bf, Wc1bf,
                                             aggbf, fsum, cnt);
    node_kernel<<<(NN + 63) / 64, 256, 0, stream>>>(hbf, bn1, bn2, bv1, Wv2, bv2,
                                                    Wn1bf, Wn2bf, Wv1bf,
                                                    aggbf, fsum, cnt, out);
}